// Round 11
// baseline (337.411 us; speedup 1.0000x reference)
//
#include <hip/hip_runtime.h>
#include <hip/hip_bf16.h>
#include <math.h>
#include <stdint.h>

#define HID 256
#define HEADS 8
#define BN_EPS 1e-5f
#define NEG 0.2f
#define WCAP 96    // per-wave edge cache (deg ~ Poisson(16)+1; fallback beyond)
#define SEPT 8     // scan: elements per thread
#define SCHUNK (256 * SEPT)

typedef _Float16 hv8 __attribute__((ext_vector_type(8)));
typedef float f32x4 __attribute__((ext_vector_type(4)));

__device__ __forceinline__ float lrelu(float x) { return x > 0.f ? x : NEG * x; }
__device__ __forceinline__ float eluf(float x)  { return x > 0.f ? x : expm1f(x); }

__device__ __forceinline__ unsigned short f2h(float f) {
    _Float16 h = (_Float16)f;                       // v_cvt_f16_f32, RNE
    union { _Float16 h; unsigned short u; } c; c.h = h;
    return c.u;
}
__device__ __forceinline__ float h2f(unsigned short u) {
    union { unsigned short u; _Float16 h; } c; c.u = u;
    return (float)c.h;
}
__device__ __forceinline__ unsigned int pk2h(float lo, float hi) {
    return (unsigned int)f2h(lo) | ((unsigned int)f2h(hi) << 16);
}

// acc += f16(lo/hi half of pk) * al   -- one VALU op, no unpack
#define FMAMIX_LO(acc, pk, al) \
    asm("v_fma_mix_f32 %0, %1, %2, %0 op_sel:[0,0,0] op_sel_hi:[1,0,0]" \
        : "+v"(acc) : "v"(pk), "v"(al))
#define FMAMIX_HI(acc, pk, al) \
    asm("v_fma_mix_f32 %0, %1, %2, %0 op_sel:[1,0,0] op_sel_hi:[1,0,0]" \
        : "+v"(acc) : "v"(pk), "v"(al))

// ---------------- CSR build ----------------

__global__ __launch_bounds__(256) void degree_kernel(const int* __restrict__ ei,
                                                     int* __restrict__ deg,
                                                     int E, int EE) {
    int e = blockIdx.x * 256 + threadIdx.x;
    if (e >= EE) return;
    int d = (e < E) ? ei[E + e] : (e - E);
    atomicAdd(&deg[d], 1);
}

__global__ __launch_bounds__(256) void scan1_kernel(const int* __restrict__ deg,
                                                    int* __restrict__ bsum, int N) {
    __shared__ int part[256];
    int t = threadIdx.x;
    int base = blockIdx.x * SCHUNK + t * SEPT;
    int s = 0;
    if (base + SEPT <= N) {
        int4 a = *(const int4*)&deg[base];
        int4 c = *(const int4*)&deg[base + 4];
        s = a.x + a.y + a.z + a.w + c.x + c.y + c.z + c.w;
    } else {
#pragma unroll
        for (int i = 0; i < SEPT; ++i) {
            int j = base + i;
            if (j < N) s += deg[j];
        }
    }
    part[t] = s;
    __syncthreads();
    for (int d = 128; d > 0; d >>= 1) {
        if (t < d) part[t] += part[t + d];
        __syncthreads();
    }
    if (t == 0) bsum[blockIdx.x] = part[0];
}

__global__ __launch_bounds__(256) void scan2_kernel(int* __restrict__ bsum,
                                                    int* __restrict__ offs,
                                                    int nb, int N) {
    __shared__ int part[256];
    int t = threadIdx.x;
    int v = (t < nb) ? bsum[t] : 0;
    part[t] = v;
    __syncthreads();
    for (int d = 1; d < 256; d <<= 1) {
        int o = (t >= d) ? part[t - d] : 0;
        __syncthreads();
        part[t] += o;
        __syncthreads();
    }
    if (t < nb) bsum[t] = part[t] - v;
    if (t == 255) offs[N] = part[255];
}

__global__ __launch_bounds__(256) void scan3_kernel(const int* __restrict__ deg,
                                                    const int* __restrict__ bsum,
                                                    int* __restrict__ offs, int N) {
    __shared__ int part[256];
    int t = threadIdx.x;
    int base = blockIdx.x * SCHUNK + t * SEPT;
    int loc[SEPT];
    int s = 0;
#pragma unroll
    for (int i = 0; i < SEPT; ++i) {
        int j = base + i;
        int d = (j < N) ? deg[j] : 0;
        loc[i] = s;
        s += d;
    }
    part[t] = s;
    __syncthreads();
    for (int d = 1; d < 256; d <<= 1) {
        int o = (t >= d) ? part[t - d] : 0;
        __syncthreads();
        part[t] += o;
        __syncthreads();
    }
    int ex = part[t] - s + bsum[blockIdx.x];
#pragma unroll
    for (int i = 0; i < SEPT; ++i) {
        int j = base + i;
        if (j < N) offs[j] = ex + loc[i];
    }
}

__global__ __launch_bounds__(256) void scatter_kernel(const int* __restrict__ ei,
                                                      const int* __restrict__ offs,
                                                      int* __restrict__ cur,
                                                      int* __restrict__ csr_src,
                                                      int E, int EE) {
    int e = blockIdx.x * 256 + threadIdx.x;
    if (e >= EE) return;
    int s = (e < E) ? ei[e] : (e - E);
    int d = (e < E) ? ei[E + e] : (e - E);
    int pos = offs[d] + atomicAdd(&cur[d], 1);
    csr_src[pos] = s;
}

// ---------------- fused prologue: all weight prep in one launch ----------------
__device__ __forceinline__ void wfrag_body(const float* __restrict__ W,
                                           const float* __restrict__ g,
                                           const float* __restrict__ v,
                                           unsigned short* __restrict__ frag,
                                           int tile, int l) {
    int ct = tile & 15, kt = tile >> 4;
    int c = ct * 16 + (l & 15);
    int k0 = kt * 32 + (l >> 4) * 8;
    float val[8];
#pragma unroll
    for (int j = 0; j < 8; ++j) {
        float s = g[k0 + j] * rsqrtf(v[k0 + j] + BN_EPS);
        val[j] = W[(size_t)(k0 + j) * HID + c] * s;
    }
    uint4 o;
    o.x = pk2h(val[0], val[1]);
    o.y = pk2h(val[2], val[3]);
    o.z = pk2h(val[4], val[5]);
    o.w = pk2h(val[6], val[7]);
    *(uint4*)&frag[((size_t)tile * 64 + l) * 8] = o;
}

__global__ __launch_bounds__(256) void prep_kernel(
    const float* __restrict__ W1, const float* __restrict__ bn1_g,
    const float* __restrict__ bn1_b, const float* __restrict__ bn1_m,
    const float* __restrict__ bn1_v,
    const float* __restrict__ W2, const float* __restrict__ bn2_g,
    const float* __restrict__ bn2_b, const float* __restrict__ bn2_m,
    const float* __restrict__ bn2_v,
    const float* __restrict__ g3, const float* __restrict__ b3,
    const float* __restrict__ m3, const float* __restrict__ v3,
    const float* __restrict__ skip_W, const float* __restrict__ skip_b,
    const float* __restrict__ p1_W, const float* __restrict__ p1_b,
    unsigned short* __restrict__ wf1, unsigned short* __restrict__ wf2,
    unsigned short* __restrict__ hf, float* __restrict__ c1,
    float* __restrict__ c2, float* __restrict__ cp) {
    int b = blockIdx.x;
    int tid = threadIdx.x;
    int sub = tid >> 6, l = tid & 63;

    if (b < 8) {
        wfrag_body(W1, bn1_g, bn1_v, wf1, b * 4 + sub, l);
    } else if (b < 40) {
        wfrag_body(W2, bn2_g, bn2_v, wf2, (b - 8) * 4 + sub, l);
    } else if (b < 45) {               // hf: 20 tiles, K=320 ([t|x] concat)
        int tile = (b - 40) * 4 + sub;
        int mt = tile & 1, kt = tile >> 1;
        int j = mt * 16 + (l & 15);
        int k0 = kt * 32 + (l >> 4) * 8;
        float val[8];
#pragma unroll
        for (int jj = 0; jj < 8; ++jj) {
            int c = k0 + jj;
            if (c < HID) {
                float s3 = g3[c] * rsqrtf(v3[c] + BN_EPS);
                val[jj] = s3 * p1_W[c * 32 + j];
            } else {                   // S' = skip_W @ p1_W inline
                float acc = 0.f;
                for (int cc = 0; cc < HID; ++cc)
                    acc = fmaf(skip_W[(size_t)(c - HID) * HID + cc],
                               p1_W[cc * 32 + j], acc);
                val[jj] = acc;
            }
        }
        uint4 o;
        o.x = pk2h(val[0], val[1]);
        o.y = pk2h(val[2], val[3]);
        o.z = pk2h(val[4], val[5]);
        o.w = pk2h(val[6], val[7]);
        *(uint4*)&hf[((size_t)tile * 64 + l) * 8] = o;
    } else if (b == 45) {
        float acc = 0.f;
        for (int k = 0; k < 64; ++k) {
            float s = bn1_g[k] * rsqrtf(bn1_v[k] + BN_EPS);
            acc = fmaf(bn1_b[k] - bn1_m[k] * s, W1[(size_t)k * HID + tid], acc);
        }
        c1[tid] = acc;
    } else if (b == 46) {
        float acc = 0.f;
        for (int k = 0; k < HID; ++k) {
            float s = bn2_g[k] * rsqrtf(bn2_v[k] + BN_EPS);
            acc = fmaf(bn2_b[k] - bn2_m[k] * s, W2[(size_t)k * HID + tid], acc);
        }
        c2[tid] = acc;
    } else {
        if (tid < 32) {
            float acc = p1_b[tid];
            for (int c = 0; c < HID; ++c) {
                float s3 = g3[c] * rsqrtf(v3[c] + BN_EPS);
                acc = fmaf(b3[c] - m3[c] * s3 + skip_b[c], p1_W[c * 32 + tid], acc);
            }
            cp[tid] = acc;
        }
    }
}

// ---------------- MFMA GEMM (f16, swapped): D[wcol][node] = W'^T-op x X-op ----------
// F16IN: input already f16 (row-major) -> staging is a straight 16B copy.
template <int K, bool F16IN>
__global__ __launch_bounds__(256) void gemm_mfma(
    const float* __restrict__ inf, const unsigned short* __restrict__ inh,
    const unsigned short* __restrict__ wfrag, const float* __restrict__ cvec,
    const float* __restrict__ a_src, const float* __restrict__ a_dst,
    unsigned short* __restrict__ h, float* __restrict__ s_src,
    float* __restrict__ s_dst, int N) {
    constexpr int KT = K / 32;
    constexpr int OPR = K / 8;
    __shared__ unsigned short xfrag[KT * 4 * 64 * 8];
    int tid = threadIdx.x;
    int w = tid >> 6, l = tid & 63;
    int gg = l >> 4, li = l & 15;
    int base = blockIdx.x * 64;

    for (int id = tid; id < 64 * OPR; id += 256) {
        int r = id / OPR, o = id % OPR;
        int node = min(base + r, N - 1);
        uint4 pkv;
        if constexpr (F16IN) {
            pkv = *(const uint4*)&inh[(size_t)node * K + o * 8];
        } else {
            const float* p = &inf[(size_t)node * K + o * 8];
            float4 f0 = *(const float4*)p;
            float4 f1 = *(const float4*)(p + 4);
            pkv.x = pk2h(f0.x, f0.y);
            pkv.y = pk2h(f0.z, f0.w);
            pkv.z = pk2h(f1.x, f1.y);
            pkv.w = pk2h(f1.z, f1.w);
        }
        int kt = o >> 2, og = o & 3, nt = r >> 4;
        *(uint4*)&xfrag[(((kt * 4 + nt) * 64) + (r & 15) + 16 * og) * 8] = pkv;
    }
    __syncthreads();

    f32x4 acc[4][4];
#pragma unroll
    for (int mm = 0; mm < 4; ++mm) {
        float4 cv = *(const float4*)&cvec[64 * w + 16 * mm + 4 * gg];
#pragma unroll
        for (int nn = 0; nn < 4; ++nn) {
            acc[mm][nn][0] = cv.x; acc[mm][nn][1] = cv.y;
            acc[mm][nn][2] = cv.z; acc[mm][nn][3] = cv.w;
        }
    }

    for (int ks = 0; ks < KT; ++ks) {
        hv8 a[4], b[4];
#pragma unroll
        for (int mm = 0; mm < 4; ++mm)
            a[mm] = *(const hv8*)&wfrag[((size_t)(ks * 16 + w * 4 + mm) * 64 + l) * 8];
#pragma unroll
        for (int nn = 0; nn < 4; ++nn)
            b[nn] = *(const hv8*)&xfrag[((ks * 4 + nn) * 64 + l) * 8];
#pragma unroll
        for (int mm = 0; mm < 4; ++mm)
#pragma unroll
            for (int nn = 0; nn < 4; ++nn)
                acc[mm][nn] = __builtin_amdgcn_mfma_f32_16x16x32_f16(
                    a[mm], b[nn], acc[mm][nn], 0, 0, 0);
    }

    float svp[4][2], sdp[4][2];
#pragma unroll
    for (int nn = 0; nn < 4; ++nn) { svp[nn][0]=0.f; svp[nn][1]=0.f; sdp[nn][0]=0.f; sdp[nn][1]=0.f; }

#pragma unroll
    for (int mm = 0; mm < 4; ++mm) {
        int cb = 64 * w + 16 * mm + 4 * gg;
        float4 as4 = *(const float4*)&a_src[cb];
        float4 ad4 = *(const float4*)&a_dst[cb];
        int hp = mm >> 1;
#pragma unroll
        for (int nn = 0; nn < 4; ++nn) {
            f32x4 A = acc[mm][nn];
            svp[nn][hp] += A[0]*as4.x + A[1]*as4.y + A[2]*as4.z + A[3]*as4.w;
            sdp[nn][hp] += A[0]*ad4.x + A[1]*ad4.y + A[2]*ad4.z + A[3]*ad4.w;
            int node = base + 16 * nn + li;
            if (node < N) {
                ushort4 pkv;
                pkv.x = f2h(A[0]); pkv.y = f2h(A[1]);
                pkv.z = f2h(A[2]); pkv.w = f2h(A[3]);
                *(ushort4*)&h[(size_t)node * HID + cb] = pkv;
            }
        }
    }
#pragma unroll
    for (int nn = 0; nn < 4; ++nn)
#pragma unroll
        for (int hp = 0; hp < 2; ++hp) {
            svp[nn][hp] += __shfl_xor(svp[nn][hp], 16);
            svp[nn][hp] += __shfl_xor(svp[nn][hp], 32);
            sdp[nn][hp] += __shfl_xor(sdp[nn][hp], 16);
            sdp[nn][hp] += __shfl_xor(sdp[nn][hp], 32);
        }
    if (gg == 0) {
#pragma unroll
        for (int nn = 0; nn < 4; ++nn) {
            int node = base + 16 * nn + li;
            if (node < N) {
#pragma unroll
                for (int hp = 0; hp < 2; ++hp) {
                    s_src[node * HEADS + 2 * w + hp] = svp[nn][hp];
                    s_dst[node * HEADS + 2 * w + hp] = sdp[nn][hp];
                }
            }
        }
    }
}

// ---------------- agg: one WAVE per dst node; f16 in/out; fma_mix inner ----------
__global__ __launch_bounds__(256) void agg_kernel(
    const unsigned short* __restrict__ h, const float* __restrict__ s_src,
    const float* __restrict__ s_dst, const int* __restrict__ offs,
    const int* __restrict__ csr_src, const float* __restrict__ bias,
    unsigned short* __restrict__ outp, int N) {
    __shared__ float al_lds[4][WCAP][8];
    __shared__ int   u_lds[4][WCAP];
    __shared__ float mi_lds[4][16];     // [0..7]=max, [8..15]=inv
    int tid = threadIdx.x;
    int w = tid >> 6, l = tid & 63;
    int vtx = blockIdx.x * 4 + w;
    if (vtx >= N) return;               // wave-uniform
    int beg = offs[vtx], end = offs[vtx + 1];
    int deg = end - beg;
    int dc = min(deg, WCAP);

    int headA = l & 7, slot = l >> 3;
    float sdv = s_dst[vtx * HEADS + headA];

    // max pass (+ cache u and raw scores)
    float m = -3.0e38f;
    for (int e = slot; e < deg; e += 8) {
        int u = csr_src[beg + e];
        float sc = lrelu(s_src[u * HEADS + headA] + sdv);
        if (e < WCAP) {
            if (headA == 0) u_lds[w][e] = u;
            al_lds[w][e][headA] = sc;
        }
        m = fmaxf(m, sc);
    }
    m = fmaxf(m, __shfl_xor(m, 8));
    m = fmaxf(m, __shfl_xor(m, 16));
    m = fmaxf(m, __shfl_xor(m, 32));

    // exp+sum pass: one exp per (edge, head); alphas left unnormalized
    float s = 0.f;
    for (int e = slot; e < dc; e += 8) {
        float p = __expf(al_lds[w][e][headA] - m);
        al_lds[w][e][headA] = p;
        s += p;
    }
    for (int e = WCAP + slot; e < deg; e += 8) {
        int u = csr_src[beg + e];
        s += __expf(lrelu(s_src[u * HEADS + headA] + sdv) - m);
    }
    s += __shfl_xor(s, 8);
    s += __shfl_xor(s, 16);
    s += __shfl_xor(s, 32);
    if (slot == 0) {
        mi_lds[w][headA] = m;
        mi_lds[w][8 + headA] = 1.f / s;
    }
    __builtin_amdgcn_wave_barrier();    // order LDS writes (pass A) vs reads (pass B)

    // pass B: two 32-lane groups walk alternate edges; lane owns 8 cols (16B f16)
    int grp = l >> 5, gl = l & 31;
    int hd = gl >> 2;
    float a0 = 0.f, a1 = 0.f, a2 = 0.f, a3 = 0.f;
    float a4 = 0.f, a5 = 0.f, a6 = 0.f, a7 = 0.f;
#pragma unroll 2
    for (int e = grp; e < dc; e += 2) {
        int u = u_lds[w][e];
        float al = al_lds[w][e][hd];
        uint4 hv = *(const uint4*)&h[(size_t)u * HID + 8 * gl];
        FMAMIX_LO(a0, hv.x, al); FMAMIX_HI(a1, hv.x, al);
        FMAMIX_LO(a2, hv.y, al); FMAMIX_HI(a3, hv.y, al);
        FMAMIX_LO(a4, hv.z, al); FMAMIX_HI(a5, hv.z, al);
        FMAMIX_LO(a6, hv.w, al); FMAMIX_HI(a7, hv.w, al);
    }
    if (deg > WCAP) {                   // fallback (never for this graph)
        float mh = mi_lds[w][hd];
        float sdh = s_dst[vtx * HEADS + hd];
        for (int e = WCAP + grp; e < deg; e += 2) {
            int u = csr_src[beg + e];
            float al = __expf(lrelu(s_src[u * HEADS + hd] + sdh) - mh);
            uint4 hv = *(const uint4*)&h[(size_t)u * HID + 8 * gl];
            FMAMIX_LO(a0, hv.x, al); FMAMIX_HI(a1, hv.x, al);
            FMAMIX_LO(a2, hv.y, al); FMAMIX_HI(a3, hv.y, al);
            FMAMIX_LO(a4, hv.z, al); FMAMIX_HI(a5, hv.z, al);
            FMAMIX_LO(a6, hv.w, al); FMAMIX_HI(a7, hv.w, al);
        }
    }
    a0 += __shfl_xor(a0, 32); a1 += __shfl_xor(a1, 32);
    a2 += __shfl_xor(a2, 32); a3 += __shfl_xor(a3, 32);
    a4 += __shfl_xor(a4, 32); a5 += __shfl_xor(a5, 32);
    a6 += __shfl_xor(a6, 32); a7 += __shfl_xor(a7, 32);
    if (grp == 0) {
        float inv = mi_lds[w][8 + hd];
        float4 b0 = *(const float4*)&bias[8 * gl];
        float4 b1 = *(const float4*)&bias[8 * gl + 4];
        uint4 ov;
        ov.x = pk2h(eluf(a0 * inv + b0.x), eluf(a1 * inv + b0.y));
        ov.y = pk2h(eluf(a2 * inv + b0.z), eluf(a3 * inv + b0.w));
        ov.z = pk2h(eluf(a4 * inv + b1.x), eluf(a5 * inv + b1.y));
        ov.w = pk2h(eluf(a6 * inv + b1.z), eluf(a7 * inv + b1.w));
        *(uint4*)&outp[(size_t)vtx * HID + 8 * gl] = ov;
    }
}

// ---------------- head: q = [t|x] @ hfrag + c'; out = relu(q) @ p2_W + p2_b ----------
__global__ __launch_bounds__(256) void final_mfma(
    const unsigned short* __restrict__ t_in, const float* __restrict__ x,
    const unsigned short* __restrict__ hf, const float* __restrict__ cp,
    const float* __restrict__ p2_W, const float* __restrict__ p2_b,
    float* __restrict__ outp, int N) {
    constexpr int KT = 10;
    __shared__ unsigned short xfrag[KT * 4 * 64 * 8];
    int tid = threadIdx.x;
    int w = tid >> 6, l = tid & 63;
    int gg = l >> 4, li = l & 15;
    int base = blockIdx.x * 64;

    for (int id = tid; id < 64 * 40; id += 256) {
        int r = id / 40, o = id % 40;
        int node = min(base + r, N - 1);
        uint4 pkv;
        if (o < 32) {
            pkv = *(const uint4*)&t_in[(size_t)node * HID + o * 8];
        } else {
            const float* p = &x[(size_t)node * 64 + (o - 32) * 8];
            float4 f0 = *(const float4*)p;
            float4 f1 = *(const float4*)(p + 4);
            pkv.x = pk2h(f0.x, f0.y);
            pkv.y = pk2h(f0.z, f0.w);
            pkv.z = pk2h(f1.x, f1.y);
            pkv.w = pk2h(f1.z, f1.w);
        }
        int kt = o >> 2, og = o & 3, nt = r >> 4;
        *(uint4*)&xfrag[(((kt * 4 + nt) * 64) + (r & 15) + 16 * og) * 8] = pkv;
    }
    __syncthreads();

    f32x4 acc[2];
#pragma unroll
    for (int mt = 0; mt < 2; ++mt) {
        float4 cv = *(const float4*)&cp[mt * 16 + 4 * gg];
        acc[mt][0] = cv.x; acc[mt][1] = cv.y; acc[mt][2] = cv.z; acc[mt][3] = cv.w;
    }

    for (int kt = 0; kt < KT; ++kt) {
        hv8 b = *(const hv8*)&xfrag[((kt * 4 + w) * 64 + l) * 8];
#pragma unroll
        for (int mt = 0; mt < 2; ++mt) {
            hv8 a = *(const hv8*)&hf[((size_t)(kt * 2 + mt) * 64 + l) * 8];
            acc[mt] = __builtin_amdgcn_mfma_f32_16x16x32_f16(a, b, acc[mt], 0, 0, 0);
        }
    }

    float po = 0.f;
#pragma unroll
    for (int mt = 0; mt < 2; ++mt) {
        float4 p2v = *(const float4*)&p2_W[mt * 16 + 4 * gg];
        po += fmaxf(acc[mt][0], 0.f) * p2v.x;
        po += fmaxf(acc[mt][1], 0.f) * p2v.y;
        po += fmaxf(acc[mt][2], 0.f) * p2v.z;
        po += fmaxf(acc[mt][3], 0.f) * p2v.w;
    }
    po += __shfl_xor(po, 16);
    po += __shfl_xor(po, 32);
    int node = base + 16 * w + li;
    if (gg == 0 && node < N) outp[node] = po + p2_b[0];
}

// ---------------- launch ----------------

extern "C" void kernel_launch(void* const* d_in, const int* in_sizes, int n_in,
                              void* d_out, int out_size, void* d_ws, size_t ws_size,
                              hipStream_t stream) {
    const float* x      = (const float*)d_in[0];
    const int*   ei     = (const int*)  d_in[1];
    const float* bn1_g  = (const float*)d_in[2];
    const float* bn1_b  = (const float*)d_in[3];
    const float* bn1_m  = (const float*)d_in[4];
    const float* bn1_v  = (const float*)d_in[5];
    const float* W1     = (const float*)d_in[6];
    const float* a1_src = (const float*)d_in[7];
    const float* a1_dst = (const float*)d_in[8];
    const float* b1     = (const float*)d_in[9];
    const float* bn2_g  = (const float*)d_in[10];
    const float* bn2_b  = (const float*)d_in[11];
    const float* bn2_m  = (const float*)d_in[12];
    const float* bn2_v  = (const float*)d_in[13];
    const float* W2     = (const float*)d_in[14];
    const float* a2_src = (const float*)d_in[15];
    const float* a2_dst = (const float*)d_in[16];
    const float* b2     = (const float*)d_in[17];
    const float* bn3_g  = (const float*)d_in[18];
    const float* bn3_b  = (const float*)d_in[19];
    const float* bn3_m  = (const float*)d_in[20];
    const float* bn3_v  = (const float*)d_in[21];
    const float* skip_W = (const float*)d_in[22];
    const float* skip_b = (const float*)d_in[23];
    const float* p1_W   = (const float*)d_in[24];
    const float* p1_b   = (const float*)d_in[25];
    const float* p2_W   = (const float*)d_in[26];
    const float* p2_b   = (const float*)d_in[27];

    int N = in_sizes[0] / 64;
    int E = in_sizes[1] / 2;
    int EE = E + N;

    uintptr_t w = (uintptr_t)d_ws;
    auto carve = [&](size_t bytes) -> void* {
        uintptr_t p = w;
        w += (bytes + 255) & ~(size_t)255;
        return (void*)p;
    };
    int*   deg  = (int*)carve((size_t)N * 4);
    int*   cur  = (int*)carve((size_t)N * 4);
    int*   offs = (int*)carve(((size_t)N + 1) * 4);
    int*   csr  = (int*)carve((size_t)EE * 4);
    int*   bsum = (int*)carve((size_t)256 * 4);
    float* ssrc = (float*)carve((size_t)N * HEADS * 4);
    float* sdst = (float*)carve((size_t)N * HEADS * 4);
    unsigned short* wf1 = (unsigned short*)carve((size_t)2 * 16 * 64 * 8 * 2);
    unsigned short* wf2 = (unsigned short*)carve((size_t)8 * 16 * 64 * 8 * 2);
    unsigned short* hf  = (unsigned short*)carve((size_t)20 * 64 * 8 * 2);
    float* c1   = (float*)carve((size_t)HID * 4);
    float* c2   = (float*)carve((size_t)HID * 4);
    float* cp   = (float*)carve((size_t)32 * 4);
    unsigned short* hbf = (unsigned short*)carve((size_t)N * HID * 2);
    unsigned short* tbuf = (unsigned short*)carve((size_t)N * HID * 2);

    hipMemsetAsync(deg, 0, ((size_t)N * 4 + 255 & ~(size_t)255) + (size_t)N * 4, stream);

    prep_kernel<<<48, 256, 0, stream>>>(
        W1, bn1_g, bn1_b, bn1_m, bn1_v,
        W2, bn2_g, bn2_b, bn2_m, bn2_v,
        bn3_g, bn3_b, bn3_m, bn3_v, skip_W, skip_b, p1_W, p1_b,
        wf1, wf2, hf, c1, c2, cp);

    int eblk = (EE + 255) / 256;
    int nb = (N + SCHUNK - 1) / SCHUNK;
    degree_kernel<<<eblk, 256, 0, stream>>>(ei, deg, E, EE);
    scan1_kernel<<<nb, 256, 0, stream>>>(deg, bsum, N);
    scan2_kernel<<<1, 256, 0, stream>>>(bsum, offs, nb, N);
    scan3_kernel<<<nb, 256, 0, stream>>>(deg, bsum, offs, N);
    scatter_kernel<<<eblk, 256, 0, stream>>>(ei, offs, cur, csr, E, EE);

    int gblk = (N + 63) / 64;
    int ablk = (N + 3) / 4;
    // layer 1
    gemm_mfma<64, false><<<gblk, 256, 0, stream>>>(x, nullptr, wf1, c1,
                                                   a1_src, a1_dst,
                                                   hbf, ssrc, sdst, N);
    agg_kernel<<<ablk, 256, 0, stream>>>(hbf, ssrc, sdst, offs, csr, b1, tbuf, N);

    // layer 2 (f16 input)
    gemm_mfma<HID, true><<<gblk, 256, 0, stream>>>(nullptr, tbuf, wf2, c2,
                                                   a2_src, a2_dst,
                                                   hbf, ssrc, sdst, N);
    agg_kernel<<<ablk, 256, 0, stream>>>(hbf, ssrc, sdst, offs, csr, b2, tbuf, N);

    // head (fully folded, f16 t)
    final_mfma<<<gblk, 256, 0, stream>>>(tbuf, x, hf, cp, p2_W, p2_b,
                                         (float*)d_out, N);
}

// Round 13
// 319.230 us; speedup vs baseline: 1.0570x; 1.0570x over previous
//
#include <hip/hip_runtime.h>
#include <hip/hip_bf16.h>
#include <math.h>
#include <stdint.h>

#define HID 256
#define HEADS 8
#define BN_EPS 1e-5f
#define NEG 0.2f
#define WCAP 96    // per-wave edge cache (deg ~ Poisson(16)+1; fallback beyond)
#define SEPT 8     // scan: elements per thread
#define SCHUNK (256 * SEPT)

typedef _Float16 hv8 __attribute__((ext_vector_type(8)));
typedef __fp16 fv2 __attribute__((ext_vector_type(2)));
typedef float f32x4 __attribute__((ext_vector_type(4)));

__device__ __forceinline__ float lrelu(float x) { return x > 0.f ? x : NEG * x; }
__device__ __forceinline__ float eluf(float x)  { return x > 0.f ? x : __expf(x) - 1.f; }

__device__ __forceinline__ unsigned short f2h(float f) {
    _Float16 h = (_Float16)f;                       // v_cvt_f16_f32, RNE
    union { _Float16 h; unsigned short u; } c; c.h = h;
    return c.u;
}
__device__ __forceinline__ unsigned int pk2h(float lo, float hi) {   // RNE (weights)
    return (unsigned int)f2h(lo) | ((unsigned int)f2h(hi) << 16);
}
__device__ __forceinline__ unsigned int pkrtz(float lo, float hi) {  // 1-inst pack
    fv2 r = __builtin_amdgcn_cvt_pkrtz(lo, hi);
    union { fv2 h; unsigned int u; } c; c.h = r;
    return c.u;
}

// acc += f16(lo/hi half of pk) * al   -- one VALU op, no unpack
#define FMAMIX_LO(acc, pk, al) \
    asm("v_fma_mix_f32 %0, %1, %2, %0 op_sel:[0,0,0] op_sel_hi:[1,0,0]" \
        : "+v"(acc) : "v"(pk), "v"(al))
#define FMAMIX_HI(acc, pk, al) \
    asm("v_fma_mix_f32 %0, %1, %2, %0 op_sel:[1,0,0] op_sel_hi:[1,0,0]" \
        : "+v"(acc) : "v"(pk), "v"(al))
#define FMAMIX4(q, al) \
    FMAMIX_LO(a0, q.x, al); FMAMIX_HI(a1, q.x, al); \
    FMAMIX_LO(a2, q.y, al); FMAMIX_HI(a3, q.y, al); \
    FMAMIX_LO(a4, q.z, al); FMAMIX_HI(a5, q.z, al); \
    FMAMIX_LO(a6, q.w, al); FMAMIX_HI(a7, q.w, al)

// ---------------- CSR scan ----------------

__global__ __launch_bounds__(256) void scan1_kernel(const int* __restrict__ deg,
                                                    int* __restrict__ bsum, int N) {
    __shared__ int part[256];
    int t = threadIdx.x;
    int base = blockIdx.x * SCHUNK + t * SEPT;
    int s = 0;
    if (base + SEPT <= N) {
        int4 a = *(const int4*)&deg[base];
        int4 c = *(const int4*)&deg[base + 4];
        s = a.x + a.y + a.z + a.w + c.x + c.y + c.z + c.w;
    } else {
#pragma unroll
        for (int i = 0; i < SEPT; ++i) {
            int j = base + i;
            if (j < N) s += deg[j];
        }
    }
    part[t] = s;
    __syncthreads();
    for (int d = 128; d > 0; d >>= 1) {
        if (t < d) part[t] += part[t + d];
        __syncthreads();
    }
    if (t == 0) bsum[blockIdx.x] = part[0];
}

__global__ __launch_bounds__(256) void scan2_kernel(int* __restrict__ bsum,
                                                    int* __restrict__ offs,
                                                    int nb, int N) {
    __shared__ int part[256];
    int t = threadIdx.x;
    int v = (t < nb) ? bsum[t] : 0;
    part[t] = v;
    __syncthreads();
    for (int d = 1; d < 256; d <<= 1) {
        int o = (t >= d) ? part[t - d] : 0;
        __syncthreads();
        part[t] += o;
        __syncthreads();
    }
    if (t < nb) bsum[t] = part[t] - v;
    if (t == 255) offs[N] = part[255];
}

__global__ __launch_bounds__(256) void scan3_kernel(const int* __restrict__ deg,
                                                    const int* __restrict__ bsum,
                                                    int* __restrict__ offs, int N) {
    __shared__ int part[256];
    int t = threadIdx.x;
    int base = blockIdx.x * SCHUNK + t * SEPT;
    int loc[SEPT];
    int s = 0;
#pragma unroll
    for (int i = 0; i < SEPT; ++i) {
        int j = base + i;
        int d = (j < N) ? deg[j] : 0;
        loc[i] = s;
        s += d;
    }
    part[t] = s;
    __syncthreads();
    for (int d = 1; d < 256; d <<= 1) {
        int o = (t >= d) ? part[t - d] : 0;
        __syncthreads();
        part[t] += o;
        __syncthreads();
    }
    int ex = part[t] - s + bsum[blockIdx.x];
#pragma unroll
    for (int i = 0; i < SEPT; ++i) {
        int j = base + i;
        if (j < N) offs[j] = ex + loc[i];
    }
}

__global__ __launch_bounds__(256) void scatter_kernel(const int* __restrict__ ei,
                                                      const int* __restrict__ offs,
                                                      int* __restrict__ cur,
                                                      int* __restrict__ csr_src,
                                                      int E, int EE) {
    int e = blockIdx.x * 256 + threadIdx.x;
    if (e >= EE) return;
    int s = (e < E) ? ei[e] : (e - E);
    int d = (e < E) ? ei[E + e] : (e - E);
    int pos = offs[d] + atomicAdd(&cur[d], 1);
    csr_src[pos] = s;
}

// ---------------- fused prologue: weight prep + degree count in one launch --------
__device__ __forceinline__ void wfrag_body(const float* __restrict__ W,
                                           const float* __restrict__ g,
                                           const float* __restrict__ v,
                                           unsigned short* __restrict__ frag,
                                           int tile, int l) {
    int ct = tile & 15, kt = tile >> 4;
    int c = ct * 16 + (l & 15);
    int k0 = kt * 32 + (l >> 4) * 8;
    float val[8];
#pragma unroll
    for (int j = 0; j < 8; ++j) {
        float s = g[k0 + j] * rsqrtf(v[k0 + j] + BN_EPS);
        val[j] = W[(size_t)(k0 + j) * HID + c] * s;
    }
    uint4 o;
    o.x = pk2h(val[0], val[1]);
    o.y = pk2h(val[2], val[3]);
    o.z = pk2h(val[4], val[5]);
    o.w = pk2h(val[6], val[7]);
    *(uint4*)&frag[((size_t)tile * 64 + l) * 8] = o;
}

__global__ __launch_bounds__(256) void prep_kernel(
    const float* __restrict__ W1, const float* __restrict__ bn1_g,
    const float* __restrict__ bn1_b, const float* __restrict__ bn1_m,
    const float* __restrict__ bn1_v,
    const float* __restrict__ W2, const float* __restrict__ bn2_g,
    const float* __restrict__ bn2_b, const float* __restrict__ bn2_m,
    const float* __restrict__ bn2_v,
    const float* __restrict__ g3, const float* __restrict__ b3,
    const float* __restrict__ m3, const float* __restrict__ v3,
    const float* __restrict__ skip_W, const float* __restrict__ skip_b,
    const float* __restrict__ p1_W, const float* __restrict__ p1_b,
    unsigned short* __restrict__ wf1, unsigned short* __restrict__ wf2,
    unsigned short* __restrict__ hf, float* __restrict__ c1,
    float* __restrict__ c2, float* __restrict__ cp,
    const int* __restrict__ ei, int* __restrict__ deg, int E, int EE) {
    int b = blockIdx.x;
    int tid = threadIdx.x;

    if (b >= 48) {                     // degree count (fused, independent of prep)
        int e = (b - 48) * 256 + tid;
        if (e < EE) {
            int d = (e < E) ? ei[E + e] : (e - E);
            atomicAdd(&deg[d], 1);
        }
        return;
    }

    int sub = tid >> 6, l = tid & 63;
    if (b < 8) {
        wfrag_body(W1, bn1_g, bn1_v, wf1, b * 4 + sub, l);
    } else if (b < 40) {
        wfrag_body(W2, bn2_g, bn2_v, wf2, (b - 8) * 4 + sub, l);
    } else if (b < 45) {               // hf: 20 tiles, K=320 ([t|x] concat)
        int tile = (b - 40) * 4 + sub;
        int mt = tile & 1, kt = tile >> 1;
        int j = mt * 16 + (l & 15);
        int k0 = kt * 32 + (l >> 4) * 8;
        float val[8];
#pragma unroll
        for (int jj = 0; jj < 8; ++jj) {
            int c = k0 + jj;
            if (c < HID) {
                float s3 = g3[c] * rsqrtf(v3[c] + BN_EPS);
                val[jj] = s3 * p1_W[c * 32 + j];
            } else {                   // S' = skip_W @ p1_W inline
                float acc = 0.f;
                for (int cc = 0; cc < HID; ++cc)
                    acc = fmaf(skip_W[(size_t)(c - HID) * HID + cc],
                               p1_W[cc * 32 + j], acc);
                val[jj] = acc;
            }
        }
        uint4 o;
        o.x = pk2h(val[0], val[1]);
        o.y = pk2h(val[2], val[3]);
        o.z = pk2h(val[4], val[5]);
        o.w = pk2h(val[6], val[7]);
        *(uint4*)&hf[((size_t)tile * 64 + l) * 8] = o;
    } else if (b == 45) {
        float acc = 0.f;
        for (int k = 0; k < 64; ++k) {
            float s = bn1_g[k] * rsqrtf(bn1_v[k] + BN_EPS);
            acc = fmaf(bn1_b[k] - bn1_m[k] * s, W1[(size_t)k * HID + tid], acc);
        }
        c1[tid] = acc;
    } else if (b == 46) {
        float acc = 0.f;
        for (int k = 0; k < HID; ++k) {
            float s = bn2_g[k] * rsqrtf(bn2_v[k] + BN_EPS);
            acc = fmaf(bn2_b[k] - bn2_m[k] * s, W2[(size_t)k * HID + tid], acc);
        }
        c2[tid] = acc;
    } else {
        if (tid < 32) {
            float acc = p1_b[tid];
            for (int c = 0; c < HID; ++c) {
                float s3 = g3[c] * rsqrtf(v3[c] + BN_EPS);
                acc = fmaf(b3[c] - m3[c] * s3 + skip_b[c], p1_W[c * 32 + tid], acc);
            }
            cp[tid] = acc;
        }
    }
}

// ---------------- MFMA GEMM (f16, swapped): D[wcol][node] = W'^T-op x X-op ----------
template <int K, bool F16IN>
__global__ __launch_bounds__(256) void gemm_mfma(
    const float* __restrict__ inf, const unsigned short* __restrict__ inh,
    const unsigned short* __restrict__ wfrag, const float* __restrict__ cvec,
    const float* __restrict__ a_src, const float* __restrict__ a_dst,
    unsigned short* __restrict__ h, float* __restrict__ s_src,
    float* __restrict__ s_dst, int N) {
    constexpr int KT = K / 32;
    constexpr int OPR = K / 8;
    __shared__ unsigned short xfrag[KT * 4 * 64 * 8];
    int tid = threadIdx.x;
    int w = tid >> 6, l = tid & 63;
    int gg = l >> 4, li = l & 15;
    int base = blockIdx.x * 64;

    for (int id = tid; id < 64 * OPR; id += 256) {
        int r = id / OPR, o = id % OPR;
        int node = min(base + r, N - 1);
        uint4 pkv;
        if constexpr (F16IN) {
            pkv = *(const uint4*)&inh[(size_t)node * K + o * 8];
        } else {
            const float* p = &inf[(size_t)node * K + o * 8];
            float4 f0 = *(const float4*)p;
            float4 f1 = *(const float4*)(p + 4);
            pkv.x = pkrtz(f0.x, f0.y);
            pkv.y = pkrtz(f0.z, f0.w);
            pkv.z = pkrtz(f1.x, f1.y);
            pkv.w = pkrtz(f1.z, f1.w);
        }
        int kt = o >> 2, og = o & 3, nt = r >> 4;
        *(uint4*)&xfrag[(((kt * 4 + nt) * 64) + (r & 15) + 16 * og) * 8] = pkv;
    }
    __syncthreads();

    f32x4 acc[4][4];
#pragma unroll
    for (int mm = 0; mm < 4; ++mm) {
        float4 cv = *(const float4*)&cvec[64 * w + 16 * mm + 4 * gg];
#pragma unroll
        for (int nn = 0; nn < 4; ++nn) {
            acc[mm][nn][0] = cv.x; acc[mm][nn][1] = cv.y;
            acc[mm][nn][2] = cv.z; acc[mm][nn][3] = cv.w;
        }
    }

    for (int ks = 0; ks < KT; ++ks) {
        hv8 a[4], b[4];
#pragma unroll
        for (int mm = 0; mm < 4; ++mm)
            a[mm] = *(const hv8*)&wfrag[((size_t)(ks * 16 + w * 4 + mm) * 64 + l) * 8];
#pragma unroll
        for (int nn = 0; nn < 4; ++nn)
            b[nn] = *(const hv8*)&xfrag[((ks * 4 + nn) * 64 + l) * 8];
#pragma unroll
        for (int mm = 0; mm < 4; ++mm)
#pragma unroll
            for (int nn = 0; nn < 4; ++nn)
                acc[mm][nn] = __builtin_amdgcn_mfma_f32_16x16x32_f16(
                    a[mm], b[nn], acc[mm][nn], 0, 0, 0);
    }

    float svp[4][2], sdp[4][2];
#pragma unroll
    for (int nn = 0; nn < 4; ++nn) { svp[nn][0]=0.f; svp[nn][1]=0.f; sdp[nn][0]=0.f; sdp[nn][1]=0.f; }

#pragma unroll
    for (int mm = 0; mm < 4; ++mm) {
        int cb = 64 * w + 16 * mm + 4 * gg;
        float4 as4 = *(const float4*)&a_src[cb];
        float4 ad4 = *(const float4*)&a_dst[cb];
        int hp = mm >> 1;
#pragma unroll
        for (int nn = 0; nn < 4; ++nn) {
            f32x4 A = acc[mm][nn];
            svp[nn][hp] += A[0]*as4.x + A[1]*as4.y + A[2]*as4.z + A[3]*as4.w;
            sdp[nn][hp] += A[0]*ad4.x + A[1]*ad4.y + A[2]*ad4.z + A[3]*ad4.w;
            int node = base + 16 * nn + li;
            if (node < N) {
                uint2 pkv2;
                pkv2.x = pkrtz(A[0], A[1]);
                pkv2.y = pkrtz(A[2], A[3]);
                *(uint2*)&h[(size_t)node * HID + cb] = pkv2;
            }
        }
    }
#pragma unroll
    for (int nn = 0; nn < 4; ++nn)
#pragma unroll
        for (int hp = 0; hp < 2; ++hp) {
            svp[nn][hp] += __shfl_xor(svp[nn][hp], 16);
            svp[nn][hp] += __shfl_xor(svp[nn][hp], 32);
            sdp[nn][hp] += __shfl_xor(sdp[nn][hp], 16);
            sdp[nn][hp] += __shfl_xor(sdp[nn][hp], 32);
        }
    if (gg == 0) {
#pragma unroll
        for (int nn = 0; nn < 4; ++nn) {
            int node = base + 16 * nn + li;
            if (node < N) {
#pragma unroll
                for (int hp = 0; hp < 2; ++hp) {
                    s_src[node * HEADS + 2 * w + hp] = svp[nn][hp];
                    s_dst[node * HEADS + 2 * w + hp] = sdp[nn][hp];
                }
            }
        }
    }
}

// ---------------- agg: one WAVE per dst node; f16; 4-deep load pipeline ----------
__global__ __launch_bounds__(256) void agg_kernel(
    const unsigned short* __restrict__ h, const float* __restrict__ s_src,
    const float* __restrict__ s_dst, const int* __restrict__ offs,
    const int* __restrict__ csr_src, const float* __restrict__ bias,
    unsigned short* __restrict__ outp, int N) {
    __shared__ float al_lds[4][WCAP][8];
    __shared__ int   u_lds[4][WCAP];
    __shared__ float mi_lds[4][16];     // [0..7]=max, [8..15]=inv
    int tid = threadIdx.x;
    int w = tid >> 6, l = tid & 63;
    int vtx = blockIdx.x * 4 + w;
    if (vtx >= N) return;               // wave-uniform
    int beg = offs[vtx], end = offs[vtx + 1];
    int deg = end - beg;
    int dc = min(deg, WCAP);

    int headA = l & 7, slot = l >> 3;
    float sdv = s_dst[vtx * HEADS + headA];

    // max pass (+ cache u and raw scores)
    float m = -3.0e38f;
    for (int e = slot; e < deg; e += 8) {
        int u = csr_src[beg + e];
        float sc = lrelu(s_src[u * HEADS + headA] + sdv);
        if (e < WCAP) {
            if (headA == 0) u_lds[w][e] = u;
            al_lds[w][e][headA] = sc;
        }
        m = fmaxf(m, sc);
    }
    m = fmaxf(m, __shfl_xor(m, 8));
    m = fmaxf(m, __shfl_xor(m, 16));
    m = fmaxf(m, __shfl_xor(m, 32));

    // exp+sum pass: one exp per (edge, head); alphas left unnormalized
    float s = 0.f;
    for (int e = slot; e < dc; e += 8) {
        float p = __expf(al_lds[w][e][headA] - m);
        al_lds[w][e][headA] = p;
        s += p;
    }
    for (int e = WCAP + slot; e < deg; e += 8) {
        int u = csr_src[beg + e];
        s += __expf(lrelu(s_src[u * HEADS + headA] + sdv) - m);
    }
    s += __shfl_xor(s, 8);
    s += __shfl_xor(s, 16);
    s += __shfl_xor(s, 32);
    if (slot == 0) {
        mi_lds[w][headA] = m;
        mi_lds[w][8 + headA] = 1.f / s;
    }
    __builtin_amdgcn_wave_barrier();    // order LDS writes (pass A) vs reads (pass B)

    // pass B: two 32-lane groups walk alternate edges; lane owns 8 cols;
    // manual 4-deep pipeline -> 4 global loads in flight.
    int grp = l >> 5, gl = l & 31;
    int hd = gl >> 2;
    float a0 = 0.f, a1 = 0.f, a2 = 0.f, a3 = 0.f;
    float a4 = 0.f, a5 = 0.f, a6 = 0.f, a7 = 0.f;
    const unsigned short* hb = h + 8 * gl;
    int e = grp;
    for (; e + 6 < dc; e += 8) {
        int u0 = u_lds[w][e];
        int u1 = u_lds[w][e + 2];
        int u2 = u_lds[w][e + 4];
        int u3 = u_lds[w][e + 6];
        float l0 = al_lds[w][e][hd];
        float l1 = al_lds[w][e + 2][hd];
        float l2 = al_lds[w][e + 4][hd];
        float l3 = al_lds[w][e + 6][hd];
        uint4 v0 = *(const uint4*)&hb[(size_t)u0 * HID];
        uint4 v1 = *(const uint4*)&hb[(size_t)u1 * HID];
        uint4 v2 = *(const uint4*)&hb[(size_t)u2 * HID];
        uint4 v3 = *(const uint4*)&hb[(size_t)u3 * HID];
        FMAMIX4(v0, l0);
        FMAMIX4(v1, l1);
        FMAMIX4(v2, l2);
        FMAMIX4(v3, l3);
    }
    for (; e < dc; e += 2) {
        int u0 = u_lds[w][e];
        float l0 = al_lds[w][e][hd];
        uint4 v0 = *(const uint4*)&hb[(size_t)u0 * HID];
        FMAMIX4(v0, l0);
    }
    if (deg > WCAP) {                   // fallback (never for this graph)
        float mh = mi_lds[w][hd];
        float sdh = s_dst[vtx * HEADS + hd];
        for (int ee = WCAP + grp; ee < deg; ee += 2) {
            int u = csr_src[beg + ee];
            float al = __expf(lrelu(s_src[u * HEADS + hd] + sdh) - mh);
            uint4 v0 = *(const uint4*)&hb[(size_t)u * HID];
            FMAMIX4(v0, al);
        }
    }
    a0 += __shfl_xor(a0, 32); a1 += __shfl_xor(a1, 32);
    a2 += __shfl_xor(a2, 32); a3 += __shfl_xor(a3, 32);
    a4 += __shfl_xor(a4, 32); a5 += __shfl_xor(a5, 32);
    a6 += __shfl_xor(a6, 32); a7 += __shfl_xor(a7, 32);

    // epilogue split across both groups: each lane handles 4 cols
    float inv = mi_lds[w][8 + hd];
    float e0 = grp ? a4 : a0;
    float e1 = grp ? a5 : a1;
    float e2 = grp ? a6 : a2;
    float e3 = grp ? a7 : a3;
    float4 bb = *(const float4*)&bias[8 * gl + 4 * grp];
    uint2 ov;
    ov.x = pkrtz(eluf(e0 * inv + bb.x), eluf(e1 * inv + bb.y));
    ov.y = pkrtz(eluf(e2 * inv + bb.z), eluf(e3 * inv + bb.w));
    *(uint2*)&outp[(size_t)vtx * HID + 8 * gl + 4 * grp] = ov;
}

// ---------------- head: q = [t|x] @ hfrag + c'; out = relu(q) @ p2_W + p2_b ----------
__global__ __launch_bounds__(256) void final_mfma(
    const unsigned short* __restrict__ t_in, const float* __restrict__ x,
    const unsigned short* __restrict__ hf, const float* __restrict__ cp,
    const float* __restrict__ p2_W, const float* __restrict__ p2_b,
    float* __restrict__ outp, int N) {
    constexpr int KT = 10;
    __shared__ unsigned short xfrag[KT * 4 * 64 * 8];
    int tid = threadIdx.x;
    int w = tid >> 6, l = tid & 63;
    int gg = l >> 4, li = l & 15;
    int base = blockIdx.x * 64;

    for (int id = tid; id < 64 * 40; id += 256) {
        int r = id / 40, o = id % 40;
        int node = min(base + r, N - 1);
        uint4 pkv;
        if (o < 32) {
            pkv = *(const uint4*)&t_in[(size_t)node * HID + o * 8];
        } else {
            const float* p = &x[(size_t)node * 64 + (o - 32) * 8];
            float4 f0 = *(const float4*)p;
            float4 f1 = *(const float4*)(p + 4);
            pkv.x = pkrtz(f0.x, f0.y);
            pkv.y = pkrtz(f0.z, f0.w);
            pkv.z = pkrtz(f1.x, f1.y);
            pkv.w = pkrtz(f1.z, f1.w);
        }
        int kt = o >> 2, og = o & 3, nt = r >> 4;
        *(uint4*)&xfrag[(((kt * 4 + nt) * 64) + (r & 15) + 16 * og) * 8] = pkv;
    }
    __syncthreads();

    f32x4 acc[2];
#pragma unroll
    for (int mt = 0; mt < 2; ++mt) {
        float4 cv = *(const float4*)&cp[mt * 16 + 4 * gg];
        acc[mt][0] = cv.x; acc[mt][1] = cv.y; acc[mt][2] = cv.z; acc[mt][3] = cv.w;
    }

    for (int kt = 0; kt < KT; ++kt) {
        hv8 b = *(const hv8*)&xfrag[((kt * 4 + w) * 64 + l) * 8];
#pragma unroll
        for (int mt = 0; mt < 2; ++mt) {
            hv8 a = *(const hv8*)&hf[((size_t)(kt * 2 + mt) * 64 + l) * 8];
            acc[mt] = __builtin_amdgcn_mfma_f32_16x16x32_f16(a, b, acc[mt], 0, 0, 0);
        }
    }

    float po = 0.f;
#pragma unroll
    for (int mt = 0; mt < 2; ++mt) {
        float4 p2v = *(const float4*)&p2_W[mt * 16 + 4 * gg];
        po += fmaxf(acc[mt][0], 0.f) * p2v.x;
        po += fmaxf(acc[mt][1], 0.f) * p2v.y;
        po += fmaxf(acc[mt][2], 0.f) * p2v.z;
        po += fmaxf(acc[mt][3], 0.f) * p2v.w;
    }
    po += __shfl_xor(po, 16);
    po += __shfl_xor(po, 32);
    int node = base + 16 * w + li;
    if (gg == 0 && node < N) outp[node] = po + p2_b[0];
}

// ---------------- launch ----------------

extern "C" void kernel_launch(void* const* d_in, const int* in_sizes, int n_in,
                              void* d_out, int out_size, void* d_ws, size_t ws_size,
                              hipStream_t stream) {
    const float* x      = (const float*)d_in[0];
    const int*   ei     = (const int*)  d_in[1];
    const float* bn1_g  = (const float*)d_in[2];
    const float* bn1_b  = (const float*)d_in[3];
    const float* bn1_m  = (const float*)d_in[4];
    const float* bn1_v  = (const float*)d_in[5];
    const float* W1     = (const float*)d_in[6];
    const float* a1_src = (const float*)d_in[7];
    const float* a1_dst = (const float*)d_in[8];
    const float* b1     = (const float*)d_in[9];
    const float* bn2_g  = (const float*)d_in[10];
    const float* bn2_b  = (const float*)d_in[11];
    const float* bn2_m  = (const float*)d_in[12];
    const float* bn2_v  = (const float*)d_in[13];
    const float* W2     = (const float*)d_in[14];
    const float* a2_src = (const float*)d_in[15];
    const float* a2_dst = (const float*)d_in[16];
    const float* b2     = (const float*)d_in[17];
    const float* bn3_g  = (const float*)d_in[18];
    const float* bn3_b  = (const float*)d_in[19];
    const float* bn3_m  = (const float*)d_in[20];
    const float* bn3_v  = (const float*)d_in[21];
    const float* skip_W = (const float*)d_in[22];
    const float* skip_b = (const float*)d_in[23];
    const float* p1_W   = (const float*)d_in[24];
    const float* p1_b   = (const float*)d_in[25];
    const float* p2_W   = (const float*)d_in[26];
    const float* p2_b   = (const float*)d_in[27];

    int N = in_sizes[0] / 64;
    int E = in_sizes[1] / 2;
    int EE = E + N;

    uintptr_t w = (uintptr_t)d_ws;
    auto carve = [&](size_t bytes) -> void* {
        uintptr_t p = w;
        w += (bytes + 255) & ~(size_t)255;
        return (void*)p;
    };
    int*   deg  = (int*)carve((size_t)N * 4);
    int*   cur  = (int*)carve((size_t)N * 4);
    int*   offs = (int*)carve(((size_t)N + 1) * 4);
    int*   csr  = (int*)carve((size_t)EE * 4);
    int*   bsum = (int*)carve((size_t)256 * 4);
    float* ssrc = (float*)carve((size_t)N * HEADS * 4);
    float* sdst = (float*)carve((size_t)N * HEADS * 4);
    unsigned short* wf1 = (unsigned short*)carve((size_t)2 * 16 * 64 * 8 * 2);
    unsigned short* wf2 = (unsigned short*)carve((size_t)8 * 16 * 64 * 8 * 2);
    unsigned short* hf  = (unsigned short*)carve((size_t)20 * 64 * 8 * 2);
    float* c1   = (float*)carve((size_t)HID * 4);
    float* c2   = (float*)carve((size_t)HID * 4);
    float* cp   = (float*)carve((size_t)32 * 4);
    unsigned short* hbf = (unsigned short*)carve((size_t)N * HID * 2);
    unsigned short* tbuf = (unsigned short*)carve((size_t)N * HID * 2);

    hipMemsetAsync(deg, 0, ((size_t)N * 4 + 255 & ~(size_t)255) + (size_t)N * 4, stream);

    // fused weight prep + degree count
    int eblk = (EE + 255) / 256;
    prep_kernel<<<48 + eblk, 256, 0, stream>>>(
        W1, bn1_g, bn1_b, bn1_m, bn1_v,
        W2, bn2_g, bn2_b, bn2_m, bn2_v,
        bn3_g, bn3_b, bn3_m, bn3_v, skip_W, skip_b, p1_W, p1_b,
        wf1, wf2, hf, c1, c2, cp, ei, deg, E, EE);

    int nb = (N + SCHUNK - 1) / SCHUNK;
    scan1_kernel<<<nb, 256, 0, stream>>>(deg, bsum, N);
    scan2_kernel<<<1, 256, 0, stream>>>(bsum, offs, nb, N);
    scan3_kernel<<<nb, 256, 0, stream>>>(deg, bsum, offs, N);
    scatter_kernel<<<eblk, 256, 0, stream>>>(ei, offs, cur, csr, E, EE);

    int gblk = (N + 63) / 64;
    int ablk = (N + 3) / 4;
    // layer 1
    gemm_mfma<64, false><<<gblk, 256, 0, stream>>>(x, nullptr, wf1, c1,
                                                   a1_src, a1_dst,
                                                   hbf, ssrc, sdst, N);
    agg_kernel<<<ablk, 256, 0, stream>>>(hbf, ssrc, sdst, offs, csr, b1, tbuf, N);

    // layer 2 (f16 input)
    gemm_mfma<HID, true><<<gblk, 256, 0, stream>>>(nullptr, tbuf, wf2, c2,
                                                   a2_src, a2_dst,
                                                   hbf, ssrc, sdst, N);
    agg_kernel<<<ablk, 256, 0, stream>>>(hbf, ssrc, sdst, offs, csr, b2, tbuf, N);

    // head (fully folded, f16 t)
    final_mfma<<<gblk, 256, 0, stream>>>(tbuf, x, hf, cp, p2_W, p2_b,
                                         (float*)d_out, N);
}

// Round 14
// 295.904 us; speedup vs baseline: 1.1403x; 1.0788x over previous
//
#include <hip/hip_runtime.h>
#include <hip/hip_bf16.h>
#include <math.h>
#include <stdint.h>

#define HID 256
#define HEADS 8
#define BN_EPS 1e-5f
#define NEG 0.2f
#define WCAP 96    // per-wave edge cache (deg ~ Poisson(16)+1; fallback beyond)
#define SEPT 8     // scan: elements per thread
#define SCHUNK (256 * SEPT)

typedef _Float16 hv8 __attribute__((ext_vector_type(8)));
typedef __fp16 fv2 __attribute__((ext_vector_type(2)));
typedef float f32x4 __attribute__((ext_vector_type(4)));

__device__ __forceinline__ float lrelu(float x) { return x > 0.f ? x : NEG * x; }
__device__ __forceinline__ float eluf(float x)  { return x > 0.f ? x : __expf(x) - 1.f; }

__device__ __forceinline__ unsigned short f2h(float f) {
    _Float16 h = (_Float16)f;                       // v_cvt_f16_f32, RNE
    union { _Float16 h; unsigned short u; } c; c.h = h;
    return c.u;
}
__device__ __forceinline__ unsigned int pk2h(float lo, float hi) {   // RNE (weights)
    return (unsigned int)f2h(lo) | ((unsigned int)f2h(hi) << 16);
}
__device__ __forceinline__ unsigned int pkrtz(float lo, float hi) {  // 1-inst pack
    fv2 r = __builtin_amdgcn_cvt_pkrtz(lo, hi);
    union { fv2 h; unsigned int u; } c; c.h = r;
    return c.u;
}

// acc += f16(lo/hi half of pk) * al   -- one VALU op, no unpack
#define FMAMIX_LO(acc, pk, al) \
    asm("v_fma_mix_f32 %0, %1, %2, %0 op_sel:[0,0,0] op_sel_hi:[1,0,0]" \
        : "+v"(acc) : "v"(pk), "v"(al))
#define FMAMIX_HI(acc, pk, al) \
    asm("v_fma_mix_f32 %0, %1, %2, %0 op_sel:[1,0,0] op_sel_hi:[1,0,0]" \
        : "+v"(acc) : "v"(pk), "v"(al))
#define FMAMIX4(q, al) \
    FMAMIX_LO(a0, q.x, al); FMAMIX_HI(a1, q.x, al); \
    FMAMIX_LO(a2, q.y, al); FMAMIX_HI(a3, q.y, al); \
    FMAMIX_LO(a4, q.z, al); FMAMIX_HI(a5, q.z, al); \
    FMAMIX_LO(a6, q.w, al); FMAMIX_HI(a7, q.w, al)

// ---------------- CSR scan ----------------

__global__ __launch_bounds__(256) void scan1_kernel(const int* __restrict__ deg,
                                                    int* __restrict__ bsum, int N) {
    __shared__ int part[256];
    int t = threadIdx.x;
    int base = blockIdx.x * SCHUNK + t * SEPT;
    int s = 0;
    if (base + SEPT <= N) {
        int4 a = *(const int4*)&deg[base];
        int4 c = *(const int4*)&deg[base + 4];
        s = a.x + a.y + a.z + a.w + c.x + c.y + c.z + c.w;
    } else {
#pragma unroll
        for (int i = 0; i < SEPT; ++i) {
            int j = base + i;
            if (j < N) s += deg[j];
        }
    }
    part[t] = s;
    __syncthreads();
    for (int d = 128; d > 0; d >>= 1) {
        if (t < d) part[t] += part[t + d];
        __syncthreads();
    }
    if (t == 0) bsum[blockIdx.x] = part[0];
}

__global__ __launch_bounds__(256) void scan2_kernel(int* __restrict__ bsum,
                                                    int* __restrict__ offs,
                                                    int nb, int N) {
    __shared__ int part[256];
    int t = threadIdx.x;
    int v = (t < nb) ? bsum[t] : 0;
    part[t] = v;
    __syncthreads();
    for (int d = 1; d < 256; d <<= 1) {
        int o = (t >= d) ? part[t - d] : 0;
        __syncthreads();
        part[t] += o;
        __syncthreads();
    }
    if (t < nb) bsum[t] = part[t] - v;
    if (t == 255) offs[N] = part[255];
}

__global__ __launch_bounds__(256) void scan3_kernel(const int* __restrict__ deg,
                                                    const int* __restrict__ bsum,
                                                    int* __restrict__ offs, int N) {
    __shared__ int part[256];
    int t = threadIdx.x;
    int base = blockIdx.x * SCHUNK + t * SEPT;
    int loc[SEPT];
    int s = 0;
#pragma unroll
    for (int i = 0; i < SEPT; ++i) {
        int j = base + i;
        int d = (j < N) ? deg[j] : 0;
        loc[i] = s;
        s += d;
    }
    part[t] = s;
    __syncthreads();
    for (int d = 1; d < 256; d <<= 1) {
        int o = (t >= d) ? part[t - d] : 0;
        __syncthreads();
        part[t] += o;
        __syncthreads();
    }
    int ex = part[t] - s + bsum[blockIdx.x];
#pragma unroll
    for (int i = 0; i < SEPT; ++i) {
        int j = base + i;
        if (j < N) offs[j] = ex + loc[i];
    }
}

__global__ __launch_bounds__(256) void scatter_kernel(const int* __restrict__ ei,
                                                      const int* __restrict__ offs,
                                                      int* __restrict__ cur,
                                                      int* __restrict__ csr_src,
                                                      int E, int EE) {
    int e = blockIdx.x * 256 + threadIdx.x;
    if (e >= EE) return;
    int s = (e < E) ? ei[e] : (e - E);
    int d = (e < E) ? ei[E + e] : (e - E);
    int pos = offs[d] + atomicAdd(&cur[d], 1);
    csr_src[pos] = s;
}

// ---------------- S' = skip_W @ p1_W  (parallel, wave-uniform skip_W s_loads) ----
__global__ __launch_bounds__(32) void sfold_kernel(const float* __restrict__ skip_W,
                                                   const float* __restrict__ p1_W,
                                                   float* __restrict__ Sp) {
    int cx = blockIdx.x, j = threadIdx.x;
    float acc = 0.f;
    for (int c = 0; c < HID; c += 4) {
        float4 sw = *(const float4*)&skip_W[(size_t)cx * HID + c];  // uniform -> s_load
        acc = fmaf(sw.x, p1_W[(c + 0) * 32 + j], acc);
        acc = fmaf(sw.y, p1_W[(c + 1) * 32 + j], acc);
        acc = fmaf(sw.z, p1_W[(c + 2) * 32 + j], acc);
        acc = fmaf(sw.w, p1_W[(c + 3) * 32 + j], acc);
    }
    Sp[cx * 32 + j] = acc;
}

// ---------------- fused prologue: weight prep + degree count in one launch --------
__device__ __forceinline__ void wfrag_body(const float* __restrict__ W,
                                           const float* __restrict__ g,
                                           const float* __restrict__ v,
                                           unsigned short* __restrict__ frag,
                                           int tile, int l) {
    int ct = tile & 15, kt = tile >> 4;
    int c = ct * 16 + (l & 15);
    int k0 = kt * 32 + (l >> 4) * 8;
    float val[8];
#pragma unroll
    for (int j = 0; j < 8; ++j) {
        float s = g[k0 + j] * rsqrtf(v[k0 + j] + BN_EPS);
        val[j] = W[(size_t)(k0 + j) * HID + c] * s;
    }
    uint4 o;
    o.x = pk2h(val[0], val[1]);
    o.y = pk2h(val[2], val[3]);
    o.z = pk2h(val[4], val[5]);
    o.w = pk2h(val[6], val[7]);
    *(uint4*)&frag[((size_t)tile * 64 + l) * 8] = o;
}

__global__ __launch_bounds__(256) void prep_kernel(
    const float* __restrict__ W1, const float* __restrict__ bn1_g,
    const float* __restrict__ bn1_b, const float* __restrict__ bn1_m,
    const float* __restrict__ bn1_v,
    const float* __restrict__ W2, const float* __restrict__ bn2_g,
    const float* __restrict__ bn2_b, const float* __restrict__ bn2_m,
    const float* __restrict__ bn2_v,
    const float* __restrict__ g3, const float* __restrict__ b3,
    const float* __restrict__ m3, const float* __restrict__ v3,
    const float* __restrict__ Sp, const float* __restrict__ skip_b,
    const float* __restrict__ p1_W, const float* __restrict__ p1_b,
    unsigned short* __restrict__ wf1, unsigned short* __restrict__ wf2,
    unsigned short* __restrict__ hf, float* __restrict__ c1,
    float* __restrict__ c2, float* __restrict__ cp,
    const int* __restrict__ ei, int* __restrict__ deg, int E, int EE) {
    int b = blockIdx.x;
    int tid = threadIdx.x;

    if (b >= 48) {                     // degree count (fused, independent of prep)
        int e = (b - 48) * 256 + tid;
        if (e < EE) {
            int d = (e < E) ? ei[E + e] : (e - E);
            atomicAdd(&deg[d], 1);
        }
        return;
    }

    int sub = tid >> 6, l = tid & 63;
    if (b < 8) {
        wfrag_body(W1, bn1_g, bn1_v, wf1, b * 4 + sub, l);
    } else if (b < 40) {
        wfrag_body(W2, bn2_g, bn2_v, wf2, (b - 8) * 4 + sub, l);
    } else if (b < 45) {               // hf: 20 tiles, K=320 ([t|x] concat)
        int tile = (b - 40) * 4 + sub;
        int mt = tile & 1, kt = tile >> 1;
        int j = mt * 16 + (l & 15);
        int k0 = kt * 32 + (l >> 4) * 8;
        float val[8];
#pragma unroll
        for (int jj = 0; jj < 8; ++jj) {
            int c = k0 + jj;
            if (c < HID) {
                float s3 = g3[c] * rsqrtf(v3[c] + BN_EPS);
                val[jj] = s3 * p1_W[c * 32 + j];
            } else {                   // precomputed S'
                val[jj] = Sp[(c - HID) * 32 + j];
            }
        }
        uint4 o;
        o.x = pk2h(val[0], val[1]);
        o.y = pk2h(val[2], val[3]);
        o.z = pk2h(val[4], val[5]);
        o.w = pk2h(val[6], val[7]);
        *(uint4*)&hf[((size_t)tile * 64 + l) * 8] = o;
    } else if (b == 45) {
        float acc = 0.f;
        for (int k = 0; k < 64; ++k) {
            float s = bn1_g[k] * rsqrtf(bn1_v[k] + BN_EPS);
            acc = fmaf(bn1_b[k] - bn1_m[k] * s, W1[(size_t)k * HID + tid], acc);
        }
        c1[tid] = acc;
    } else if (b == 46) {
        float acc = 0.f;
        for (int k = 0; k < HID; ++k) {
            float s = bn2_g[k] * rsqrtf(bn2_v[k] + BN_EPS);
            acc = fmaf(bn2_b[k] - bn2_m[k] * s, W2[(size_t)k * HID + tid], acc);
        }
        c2[tid] = acc;
    } else {
        if (tid < 32) {
            float acc = p1_b[tid];
            for (int c = 0; c < HID; ++c) {
                float s3 = g3[c] * rsqrtf(v3[c] + BN_EPS);
                acc = fmaf(b3[c] - m3[c] * s3 + skip_b[c], p1_W[c * 32 + tid], acc);
            }
            cp[tid] = acc;
        }
    }
}

// ---------------- MFMA GEMM (f16, swapped): D[wcol][node] = W'^T-op x X-op ----------
template <int K, bool F16IN>
__global__ __launch_bounds__(256) void gemm_mfma(
    const float* __restrict__ inf, const unsigned short* __restrict__ inh,
    const unsigned short* __restrict__ wfrag, const float* __restrict__ cvec,
    const float* __restrict__ a_src, const float* __restrict__ a_dst,
    unsigned short* __restrict__ h, float* __restrict__ s_src,
    float* __restrict__ s_dst, int N) {
    constexpr int KT = K / 32;
    constexpr int OPR = K / 8;
    __shared__ unsigned short xfrag[KT * 4 * 64 * 8];
    int tid = threadIdx.x;
    int w = tid >> 6, l = tid & 63;
    int gg = l >> 4, li = l & 15;
    int base = blockIdx.x * 64;

    for (int id = tid; id < 64 * OPR; id += 256) {
        int r = id / OPR, o = id % OPR;
        int node = min(base + r, N - 1);
        uint4 pkv;
        if constexpr (F16IN) {
            pkv = *(const uint4*)&inh[(size_t)node * K + o * 8];
        } else {
            const float* p = &inf[(size_t)node * K + o * 8];
            float4 f0 = *(const float4*)p;
            float4 f1 = *(const float4*)(p + 4);
            pkv.x = pkrtz(f0.x, f0.y);
            pkv.y = pkrtz(f0.z, f0.w);
            pkv.z = pkrtz(f1.x, f1.y);
            pkv.w = pkrtz(f1.z, f1.w);
        }
        int kt = o >> 2, og = o & 3, nt = r >> 4;
        *(uint4*)&xfrag[(((kt * 4 + nt) * 64) + (r & 15) + 16 * og) * 8] = pkv;
    }
    __syncthreads();

    f32x4 acc[4][4];
#pragma unroll
    for (int mm = 0; mm < 4; ++mm) {
        float4 cv = *(const float4*)&cvec[64 * w + 16 * mm + 4 * gg];
#pragma unroll
        for (int nn = 0; nn < 4; ++nn) {
            acc[mm][nn][0] = cv.x; acc[mm][nn][1] = cv.y;
            acc[mm][nn][2] = cv.z; acc[mm][nn][3] = cv.w;
        }
    }

    for (int ks = 0; ks < KT; ++ks) {
        hv8 a[4], b[4];
#pragma unroll
        for (int mm = 0; mm < 4; ++mm)
            a[mm] = *(const hv8*)&wfrag[((size_t)(ks * 16 + w * 4 + mm) * 64 + l) * 8];
#pragma unroll
        for (int nn = 0; nn < 4; ++nn)
            b[nn] = *(const hv8*)&xfrag[((ks * 4 + nn) * 64 + l) * 8];
#pragma unroll
        for (int mm = 0; mm < 4; ++mm)
#pragma unroll
            for (int nn = 0; nn < 4; ++nn)
                acc[mm][nn] = __builtin_amdgcn_mfma_f32_16x16x32_f16(
                    a[mm], b[nn], acc[mm][nn], 0, 0, 0);
    }

    float svp[4][2], sdp[4][2];
#pragma unroll
    for (int nn = 0; nn < 4; ++nn) { svp[nn][0]=0.f; svp[nn][1]=0.f; sdp[nn][0]=0.f; sdp[nn][1]=0.f; }

#pragma unroll
    for (int mm = 0; mm < 4; ++mm) {
        int cb = 64 * w + 16 * mm + 4 * gg;
        float4 as4 = *(const float4*)&a_src[cb];
        float4 ad4 = *(const float4*)&a_dst[cb];
        int hp = mm >> 1;
#pragma unroll
        for (int nn = 0; nn < 4; ++nn) {
            f32x4 A = acc[mm][nn];
            svp[nn][hp] += A[0]*as4.x + A[1]*as4.y + A[2]*as4.z + A[3]*as4.w;
            sdp[nn][hp] += A[0]*ad4.x + A[1]*ad4.y + A[2]*ad4.z + A[3]*ad4.w;
            int node = base + 16 * nn + li;
            if (node < N) {
                uint2 pkv2;
                pkv2.x = pkrtz(A[0], A[1]);
                pkv2.y = pkrtz(A[2], A[3]);
                *(uint2*)&h[(size_t)node * HID + cb] = pkv2;
            }
        }
    }
#pragma unroll
    for (int nn = 0; nn < 4; ++nn)
#pragma unroll
        for (int hp = 0; hp < 2; ++hp) {
            svp[nn][hp] += __shfl_xor(svp[nn][hp], 16);
            svp[nn][hp] += __shfl_xor(svp[nn][hp], 32);
            sdp[nn][hp] += __shfl_xor(sdp[nn][hp], 16);
            sdp[nn][hp] += __shfl_xor(sdp[nn][hp], 32);
        }
    if (gg == 0) {
#pragma unroll
        for (int nn = 0; nn < 4; ++nn) {
            int node = base + 16 * nn + li;
            if (node < N) {
#pragma unroll
                for (int hp = 0; hp < 2; ++hp) {
                    s_src[node * HEADS + 2 * w + hp] = svp[nn][hp];
                    s_dst[node * HEADS + 2 * w + hp] = sdp[nn][hp];
                }
            }
        }
    }
}

// ---------------- agg: one WAVE per dst node; f16; 4-deep load pipeline ----------
__global__ __launch_bounds__(256) void agg_kernel(
    const unsigned short* __restrict__ h, const float* __restrict__ s_src,
    const float* __restrict__ s_dst, const int* __restrict__ offs,
    const int* __restrict__ csr_src, const float* __restrict__ bias,
    unsigned short* __restrict__ outp, int N) {
    __shared__ float al_lds[4][WCAP][8];
    __shared__ int   u_lds[4][WCAP];
    __shared__ float mi_lds[4][16];     // [0..7]=max, [8..15]=inv
    int tid = threadIdx.x;
    int w = tid >> 6, l = tid & 63;
    int vtx = blockIdx.x * 4 + w;
    if (vtx >= N) return;               // wave-uniform
    int beg = offs[vtx], end = offs[vtx + 1];
    int deg = end - beg;
    int dc = min(deg, WCAP);

    int headA = l & 7, slot = l >> 3;
    float sdv = s_dst[vtx * HEADS + headA];

    // max pass (+ cache u and raw scores)
    float m = -3.0e38f;
    for (int e = slot; e < deg; e += 8) {
        int u = csr_src[beg + e];
        float sc = lrelu(s_src[u * HEADS + headA] + sdv);
        if (e < WCAP) {
            if (headA == 0) u_lds[w][e] = u;
            al_lds[w][e][headA] = sc;
        }
        m = fmaxf(m, sc);
    }
    m = fmaxf(m, __shfl_xor(m, 8));
    m = fmaxf(m, __shfl_xor(m, 16));
    m = fmaxf(m, __shfl_xor(m, 32));

    // exp+sum pass: one exp per (edge, head); alphas left unnormalized
    float s = 0.f;
    for (int e = slot; e < dc; e += 8) {
        float p = __expf(al_lds[w][e][headA] - m);
        al_lds[w][e][headA] = p;
        s += p;
    }
    for (int e = WCAP + slot; e < deg; e += 8) {
        int u = csr_src[beg + e];
        s += __expf(lrelu(s_src[u * HEADS + headA] + sdv) - m);
    }
    s += __shfl_xor(s, 8);
    s += __shfl_xor(s, 16);
    s += __shfl_xor(s, 32);
    if (slot == 0) {
        mi_lds[w][headA] = m;
        mi_lds[w][8 + headA] = 1.f / s;
    }
    __builtin_amdgcn_wave_barrier();    // order LDS writes (pass A) vs reads (pass B)

    // pass B: two 32-lane groups walk alternate edges; lane owns 8 cols;
    // manual 4-deep pipeline -> 4 global loads in flight.
    int grp = l >> 5, gl = l & 31;
    int hd = gl >> 2;
    float a0 = 0.f, a1 = 0.f, a2 = 0.f, a3 = 0.f;
    float a4 = 0.f, a5 = 0.f, a6 = 0.f, a7 = 0.f;
    const unsigned short* hb = h + 8 * gl;
    int e = grp;
    for (; e + 6 < dc; e += 8) {
        int u0 = u_lds[w][e];
        int u1 = u_lds[w][e + 2];
        int u2 = u_lds[w][e + 4];
        int u3 = u_lds[w][e + 6];
        float l0 = al_lds[w][e][hd];
        float l1 = al_lds[w][e + 2][hd];
        float l2 = al_lds[w][e + 4][hd];
        float l3 = al_lds[w][e + 6][hd];
        uint4 v0 = *(const uint4*)&hb[(size_t)u0 * HID];
        uint4 v1 = *(const uint4*)&hb[(size_t)u1 * HID];
        uint4 v2 = *(const uint4*)&hb[(size_t)u2 * HID];
        uint4 v3 = *(const uint4*)&hb[(size_t)u3 * HID];
        FMAMIX4(v0, l0);
        FMAMIX4(v1, l1);
        FMAMIX4(v2, l2);
        FMAMIX4(v3, l3);
    }
    for (; e < dc; e += 2) {
        int u0 = u_lds[w][e];
        float l0 = al_lds[w][e][hd];
        uint4 v0 = *(const uint4*)&hb[(size_t)u0 * HID];
        FMAMIX4(v0, l0);
    }
    if (deg > WCAP) {                   // fallback (never for this graph)
        float mh = mi_lds[w][hd];
        float sdh = s_dst[vtx * HEADS + hd];
        for (int ee = WCAP + grp; ee < deg; ee += 2) {
            int u = csr_src[beg + ee];
            float al = __expf(lrelu(s_src[u * HEADS + hd] + sdh) - mh);
            uint4 v0 = *(const uint4*)&hb[(size_t)u * HID];
            FMAMIX4(v0, al);
        }
    }
    a0 += __shfl_xor(a0, 32); a1 += __shfl_xor(a1, 32);
    a2 += __shfl_xor(a2, 32); a3 += __shfl_xor(a3, 32);
    a4 += __shfl_xor(a4, 32); a5 += __shfl_xor(a5, 32);
    a6 += __shfl_xor(a6, 32); a7 += __shfl_xor(a7, 32);

    // epilogue split across both groups: each lane handles 4 cols
    float inv = mi_lds[w][8 + hd];
    float e0 = grp ? a4 : a0;
    float e1 = grp ? a5 : a1;
    float e2 = grp ? a6 : a2;
    float e3 = grp ? a7 : a3;
    float4 bb = *(const float4*)&bias[8 * gl + 4 * grp];
    uint2 ov;
    ov.x = pkrtz(eluf(e0 * inv + bb.x), eluf(e1 * inv + bb.y));
    ov.y = pkrtz(eluf(e2 * inv + bb.z), eluf(e3 * inv + bb.w));
    *(uint2*)&outp[(size_t)vtx * HID + 8 * gl + 4 * grp] = ov;
}

// ---------------- head: q = [t|x] @ hfrag + c'; out = relu(q) @ p2_W + p2_b ----------
__global__ __launch_bounds__(256) void final_mfma(
    const unsigned short* __restrict__ t_in, const float* __restrict__ x,
    const unsigned short* __restrict__ hf, const float* __restrict__ cp,
    const float* __restrict__ p2_W, const float* __restrict__ p2_b,
    float* __restrict__ outp, int N) {
    constexpr int KT = 10;
    __shared__ unsigned short xfrag[KT * 4 * 64 * 8];
    int tid = threadIdx.x;
    int w = tid >> 6, l = tid & 63;
    int gg = l >> 4, li = l & 15;
    int base = blockIdx.x * 64;

    for (int id = tid; id < 64 * 40; id += 256) {
        int r = id / 40, o = id % 40;
        int node = min(base + r, N - 1);
        uint4 pkv;
        if (o < 32) {
            pkv = *(const uint4*)&t_in[(size_t)node * HID + o * 8];
        } else {
            const float* p = &x[(size_t)node * 64 + (o - 32) * 8];
            float4 f0 = *(const float4*)p;
            float4 f1 = *(const float4*)(p + 4);
            pkv.x = pkrtz(f0.x, f0.y);
            pkv.y = pkrtz(f0.z, f0.w);
            pkv.z = pkrtz(f1.x, f1.y);
            pkv.w = pkrtz(f1.z, f1.w);
        }
        int kt = o >> 2, og = o & 3, nt = r >> 4;
        *(uint4*)&xfrag[(((kt * 4 + nt) * 64) + (r & 15) + 16 * og) * 8] = pkv;
    }
    __syncthreads();

    f32x4 acc[2];
#pragma unroll
    for (int mt = 0; mt < 2; ++mt) {
        float4 cv = *(const float4*)&cp[mt * 16 + 4 * gg];
        acc[mt][0] = cv.x; acc[mt][1] = cv.y; acc[mt][2] = cv.z; acc[mt][3] = cv.w;
    }

    for (int kt = 0; kt < KT; ++kt) {
        hv8 b = *(const hv8*)&xfrag[((kt * 4 + w) * 64 + l) * 8];
#pragma unroll
        for (int mt = 0; mt < 2; ++mt) {
            hv8 a = *(const hv8*)&hf[((size_t)(kt * 2 + mt) * 64 + l) * 8];
            acc[mt] = __builtin_amdgcn_mfma_f32_16x16x32_f16(a, b, acc[mt], 0, 0, 0);
        }
    }

    float po = 0.f;
#pragma unroll
    for (int mt = 0; mt < 2; ++mt) {
        float4 p2v = *(const float4*)&p2_W[mt * 16 + 4 * gg];
        po += fmaxf(acc[mt][0], 0.f) * p2v.x;
        po += fmaxf(acc[mt][1], 0.f) * p2v.y;
        po += fmaxf(acc[mt][2], 0.f) * p2v.z;
        po += fmaxf(acc[mt][3], 0.f) * p2v.w;
    }
    po += __shfl_xor(po, 16);
    po += __shfl_xor(po, 32);
    int node = base + 16 * w + li;
    if (gg == 0 && node < N) outp[node] = po + p2_b[0];
}

// ---------------- launch ----------------

extern "C" void kernel_launch(void* const* d_in, const int* in_sizes, int n_in,
                              void* d_out, int out_size, void* d_ws, size_t ws_size,
                              hipStream_t stream) {
    const float* x      = (const float*)d_in[0];
    const int*   ei     = (const int*)  d_in[1];
    const float* bn1_g  = (const float*)d_in[2];
    const float* bn1_b  = (const float*)d_in[3];
    const float* bn1_m  = (const float*)d_in[4];
    const float* bn1_v  = (const float*)d_in[5];
    const float* W1     = (const float*)d_in[6];
    const float* a1_src = (const float*)d_in[7];
    const float* a1_dst = (const float*)d_in[8];
    const float* b1     = (const float*)d_in[9];
    const float* bn2_g  = (const float*)d_in[10];
    const float* bn2_b  = (const float*)d_in[11];
    const float* bn2_m  = (const float*)d_in[12];
    const float* bn2_v  = (const float*)d_in[13];
    const float* W2     = (const float*)d_in[14];
    const float* a2_src = (const float*)d_in[15];
    const float* a2_dst = (const float*)d_in[16];
    const float* b2     = (const float*)d_in[17];
    const float* bn3_g  = (const float*)d_in[18];
    const float* bn3_b  = (const float*)d_in[19];
    const float* bn3_m  = (const float*)d_in[20];
    const float* bn3_v  = (const float*)d_in[21];
    const float* skip_W = (const float*)d_in[22];
    const float* skip_b = (const float*)d_in[23];
    const float* p1_W   = (const float*)d_in[24];
    const float* p1_b   = (const float*)d_in[25];
    const float* p2_W   = (const float*)d_in[26];
    const float* p2_b   = (const float*)d_in[27];

    int N = in_sizes[0] / 64;
    int E = in_sizes[1] / 2;
    int EE = E + N;

    uintptr_t w = (uintptr_t)d_ws;
    auto carve = [&](size_t bytes) -> void* {
        uintptr_t p = w;
        w += (bytes + 255) & ~(size_t)255;
        return (void*)p;
    };
    int*   deg  = (int*)carve((size_t)N * 4);
    int*   cur  = (int*)carve((size_t)N * 4);
    int*   offs = (int*)carve(((size_t)N + 1) * 4);
    int*   csr  = (int*)carve((size_t)EE * 4);
    int*   bsum = (int*)carve((size_t)256 * 4);
    float* ssrc = (float*)carve((size_t)N * HEADS * 4);
    float* sdst = (float*)carve((size_t)N * HEADS * 4);
    unsigned short* wf1 = (unsigned short*)carve((size_t)2 * 16 * 64 * 8 * 2);
    unsigned short* wf2 = (unsigned short*)carve((size_t)8 * 16 * 64 * 8 * 2);
    unsigned short* hf  = (unsigned short*)carve((size_t)20 * 64 * 8 * 2);
    float* c1   = (float*)carve((size_t)HID * 4);
    float* c2   = (float*)carve((size_t)HID * 4);
    float* cp   = (float*)carve((size_t)32 * 4);
    float* Sp   = (float*)carve((size_t)64 * 32 * 4);
    unsigned short* hbf = (unsigned short*)carve((size_t)N * HID * 2);
    unsigned short* tbuf = (unsigned short*)carve((size_t)N * HID * 2);

    hipMemsetAsync(deg, 0, ((size_t)N * 4 + 255 & ~(size_t)255) + (size_t)N * 4, stream);

    // S' fold (parallel), then fused weight prep + degree count
    sfold_kernel<<<64, 32, 0, stream>>>(skip_W, p1_W, Sp);
    int eblk = (EE + 255) / 256;
    prep_kernel<<<48 + eblk, 256, 0, stream>>>(
        W1, bn1_g, bn1_b, bn1_m, bn1_v,
        W2, bn2_g, bn2_b, bn2_m, bn2_v,
        bn3_g, bn3_b, bn3_m, bn3_v, Sp, skip_b, p1_W, p1_b,
        wf1, wf2, hf, c1, c2, cp, ei, deg, E, EE);

    int nb = (N + SCHUNK - 1) / SCHUNK;
    scan1_kernel<<<nb, 256, 0, stream>>>(deg, bsum, N);
    scan2_kernel<<<1, 256, 0, stream>>>(bsum, offs, nb, N);
    scan3_kernel<<<nb, 256, 0, stream>>>(deg, bsum, offs, N);
    scatter_kernel<<<eblk, 256, 0, stream>>>(ei, offs, cur, csr, E, EE);

    int gblk = (N + 63) / 64;
    int ablk = (N + 3) / 4;
    // layer 1
    gemm_mfma<64, false><<<gblk, 256, 0, stream>>>(x, nullptr, wf1, c1,
                                                   a1_src, a1_dst,
                                                   hbf, ssrc, sdst, N);
    agg_kernel<<<ablk, 256, 0, stream>>>(hbf, ssrc, sdst, offs, csr, b1, tbuf, N);

    // layer 2 (f16 input)
    gemm_mfma<HID, true><<<gblk, 256, 0, stream>>>(nullptr, tbuf, wf2, c2,
                                                   a2_src, a2_dst,
                                                   hbf, ssrc, sdst, N);
    agg_kernel<<<ablk, 256, 0, stream>>>(hbf, ssrc, sdst, offs, csr, b2, tbuf, N);

    // head (fully folded, f16 t)
    final_mfma<<<gblk, 256, 0, stream>>>(tbuf, x, hf, cp, p2_W, p2_b,
                                         (float*)d_out, N);
}